// Round 8
// baseline (221.466 us; speedup 1.0000x reference)
//
#include <hip/hip_runtime.h>

// ---------------------------------------------------------------------------
// RoPE Multihead Self-Attention  B=4 S=2048 E=1024 H=16 D=64  (bf16 internal)
// ---------------------------------------------------------------------------

typedef __attribute__((ext_vector_type(4))) float f32x4;
typedef __attribute__((ext_vector_type(8))) short bfrag;   // 8 x bf16 (4 VGPR)
typedef __attribute__((ext_vector_type(4))) short svec4;
typedef __attribute__((ext_vector_type(2))) unsigned int u32x2;

#define MFMA16(a, b, c) __builtin_amdgcn_mfma_f32_16x16x32_bf16(a, b, c, 0, 0, 0)

__device__ __forceinline__ unsigned short f2bf(float f) {
  unsigned u = __builtin_bit_cast(unsigned, f);
  u += 0x7FFFu + ((u >> 16) & 1u);            // round-to-nearest-even
  return (unsigned short)(u >> 16);
}

// async global->LDS, 16B per lane
__device__ __forceinline__ void gload16(const void* g, void* l) {
  __builtin_amdgcn_global_load_lds(
      (const __attribute__((address_space(1))) unsigned int*)g,
      (__attribute__((address_space(3))) unsigned int*)l, 16, 0, 0);
}

// ---------------------------------------------------------------------------
// K0: fp32 -> bf16 conversion of x and 4 weights + RoPE cos/sin table
// ---------------------------------------------------------------------------
__global__ __launch_bounds__(256) void prep_kernel(
    const float* __restrict__ x, const float* __restrict__ wq,
    const float* __restrict__ wk, const float* __restrict__ wv,
    const float* __restrict__ wo,
    unsigned short* __restrict__ xb, unsigned short* __restrict__ wqb,
    unsigned short* __restrict__ wkb, unsigned short* __restrict__ wvb,
    unsigned short* __restrict__ wob, float2* __restrict__ rope) {
  const int y = blockIdx.y;
  const int tid = blockIdx.x * blockDim.x + threadIdx.x;
  const int stride = gridDim.x * blockDim.x;
  if (y < 5) {
    const float* src = y == 0 ? x : y == 1 ? wq : y == 2 ? wk : y == 3 ? wv : wo;
    unsigned short* dst = y == 0 ? xb : y == 1 ? wqb : y == 2 ? wkb : y == 3 ? wvb : wob;
    const int n4 = (y == 0 ? (8192 * 1024) : (1024 * 1024)) >> 2;
    for (int i = tid; i < n4; i += stride) {
      float4 v = ((const float4*)src)[i];
      svec4 o;
      o.x = (short)f2bf(v.x); o.y = (short)f2bf(v.y);
      o.z = (short)f2bf(v.z); o.w = (short)f2bf(v.w);
      ((svec4*)dst)[i] = o;
    }
  } else {
    for (int i = tid; i < 2048 * 32; i += stride) {
      int s = i >> 5, f = i & 31;
      float invf = powf(10000.0f, -(float)f * (1.0f / 32.0f));
      float ang = (float)s * invf;
      rope[i] = make_float2(cosf(ang), sinf(ang));
    }
  }
}

// ---------------------------------------------------------------------------
// K1: QKV projection GEMM with fused RoPE (Q,K) and fused transpose (V).
// ---------------------------------------------------------------------------
__global__ __launch_bounds__(256) void gemm_qkv(
    const unsigned short* __restrict__ Xb,
    const unsigned short* __restrict__ Wq, const unsigned short* __restrict__ Wk,
    const unsigned short* __restrict__ Wv,
    const float* __restrict__ biasq, const float* __restrict__ biask,
    const float* __restrict__ biasv,
    const float2* __restrict__ rope,
    unsigned short* __restrict__ Qo, unsigned short* __restrict__ Ko,
    unsigned short* __restrict__ Vto) {
  const int z = blockIdx.z;
  __shared__ unsigned short As[128 * 64];
  __shared__ unsigned short Bs[128 * 64];
  const int t = threadIdx.x;
  const int lane = t & 63, w = t >> 6;
  const int wr = w >> 1, wc = w & 1;
  const int lc = lane & 15, lr = lane >> 4;

  int m0, n0;
  const unsigned short *Apt, *Bpt;
  if (z == 0)      { m0 = blockIdx.y * 128; n0 = blockIdx.x * 128; Apt = Xb; Bpt = Wq; }
  else if (z == 1) { m0 = blockIdx.y * 128; n0 = blockIdx.x * 128; Apt = Xb; Bpt = Wk; }
  else             { m0 = blockIdx.x * 128; n0 = blockIdx.y * 128; Apt = Wv; Bpt = Xb; }

  const int arow = t >> 3;
  const int acol = ((t & 7) << 3) ^ ((arow & 7) << 3);   // pre-swizzled source col
  const unsigned short* gA = Apt + (size_t)(m0 + arow) * 1024 + acol;
  const unsigned short* gB = Bpt + (size_t)(n0 + arow) * 1024 + acol;
  unsigned short* lA = As + t * 8;
  unsigned short* lB = Bs + t * 8;

  f32x4 acc[4][4];
#pragma unroll
  for (int m = 0; m < 4; ++m)
#pragma unroll
    for (int n = 0; n < 4; ++n) acc[m][n] = (f32x4){0.f, 0.f, 0.f, 0.f};

  const int rsw = (lc & 7) << 3;

#pragma unroll 1
  for (int kt = 0; kt < 16; ++kt) {
    __syncthreads();
#pragma unroll
    for (int c = 0; c < 4; ++c) {
      gload16(gA + (size_t)c * 32 * 1024, lA + c * 2048);
      gload16(gB + (size_t)c * 32 * 1024, lB + c * 2048);
    }
    gA += 64; gB += 64;
    __syncthreads();
#pragma unroll
    for (int ks = 0; ks < 2; ++ks) {
      bfrag af[4], bfr[4];
#pragma unroll
      for (int i = 0; i < 4; ++i)
        af[i] = *(const bfrag*)(As + (wr * 64 + i * 16 + lc) * 64 + ((ks * 32 + lr * 8) ^ rsw));
#pragma unroll
      for (int i = 0; i < 4; ++i)
        bfr[i] = *(const bfrag*)(Bs + (wc * 64 + i * 16 + lc) * 64 + ((ks * 32 + lr * 8) ^ rsw));
#pragma unroll
      for (int m = 0; m < 4; ++m)
#pragma unroll
        for (int n = 0; n < 4; ++n)
          acc[m][n] = MFMA16(af[m], bfr[n], acc[m][n]);
    }
  }

  if (z < 2) {
    // bias + RoPE + (Q only) 0.125*log2e scale; scatter to (B,H,S,D)
    const float* bias = (z == 0) ? biasq : biask;
    unsigned short* dst = (z == 0) ? Qo : Ko;
    const float qs = (z == 0) ? 0.125f * 1.44269504f : 1.0f;
    const int h = (n0 + wc * 64) >> 6;
#pragma unroll
    for (int m = 0; m < 4; ++m) {
#pragma unroll
      for (int r = 0; r < 4; ++r) {
        int row = m0 + wr * 64 + m * 16 + lr * 4 + r;   // token
        int b = row >> 11, s = row & 2047;
        const float2* trow = rope + (s << 5);
        size_t base = ((size_t)((b << 4) + h) * 2048 + s) * 64;
#pragma unroll
        for (int n = 0; n < 2; ++n) {
          int col1 = n0 + wc * 64 + n * 16 + lc;
          int d = n * 16 + lc;                           // < 32
          float a  = acc[m][n][r]     + bias[col1];
          float bb = acc[m][n + 2][r] + bias[col1 + 32];
          float2 t0 = trow[d >> 1];
          float2 t1 = trow[16 + (d >> 1)];
          dst[base + d]      = f2bf((a * t0.x - bb * t0.y) * qs);
          dst[base + d + 32] = f2bf((bb * t1.x + a * t1.y) * qs);
        }
      }
    }
  } else {
    // V: C[wcol][token] -> Vt (B,H,D,S)
#pragma unroll
    for (int m = 0; m < 4; ++m) {
#pragma unroll
      for (int r = 0; r < 4; ++r) {
        int wcol = m0 + wr * 64 + m * 16 + lr * 4 + r;
        float bv = biasv[wcol];
        int h = wcol >> 6, d = wcol & 63;
#pragma unroll
        for (int n = 0; n < 4; ++n) {
          int token = n0 + wc * 64 + n * 16 + lc;
          int b = token >> 11, s = token & 2047;
          Vto[((size_t)((b << 4) + h) * 64 + d) * 2048 + s] = f2bf(acc[m][n][r] + bv);
        }
      }
    }
  }
}

// ---------------------------------------------------------------------------
// K4: flash attention.  COMPOSED FROM TWO PROVEN-PASSING PIECES:
//   body   = round-4 kernel (16 q-rows/wave, disjoint P write->read, PASSED)
//   scheme = round-5 loop (2-deep prefetch, counted vmcnt(4) + raw s_barrier,
//            no vmcnt(0) drain in main loop, PASSED)
// P-buffer REUSE across q-halves (rounds 6/7) is abandoned: failed twice,
// mechanism unresolved.  LDS = 16K (Ks) + 16K (Vs) + 8K (P) = 40960 B
// -> 4 blocks/CU; grid 2048 = exactly 2 residency waves, no partial tail.
// ---------------------------------------------------------------------------
__global__ __launch_bounds__(256) void attn_kernel(
    const unsigned short* __restrict__ Q, const unsigned short* __restrict__ K,
    const unsigned short* __restrict__ Vt, unsigned short* __restrict__ O) {
  __shared__ unsigned short Ks[2][64 * 64];
  __shared__ unsigned short Vs[2][64 * 64];
  __shared__ unsigned short Plds[4][16 * 64];   // per-wave [q=16][key=64]
  const int t = threadIdx.x;
  const int lane = t & 63, w = t >> 6;
  const int lc = lane & 15, lr = lane >> 4;
  const int bid = blockIdx.x;                   // 2048 = 64 bh x 32 qblocks
  const int xcd = bid & 7;
  const int jj = bid >> 3;                      // 0..255
  const int bh = xcd * 8 + (jj >> 5);           // 8 heads per XCD
  const int qb = jj & 31;
  const int q0 = qb * 64 + w * 16;

  const unsigned short* Qp = Q + ((size_t)bh * 2048 + q0 + lc) * 64 + lr * 8;
  bfrag aq0 = *(const bfrag*)Qp;    // Q[q=q0+lc][d = lr*8..+7]
  bfrag aq1 = *(const bfrag*)(Qp + 32);

  f32x4 acc[4];
#pragma unroll
  for (int n = 0; n < 4; ++n) acc[n] = (f32x4){0.f, 0.f, 0.f, 0.f};
  float lsum = 0.f;                 // row-sum partial for q = q0+lc

  const unsigned short* Kg = K + (size_t)bh * 2048 * 64;
  const unsigned short* Vg = Vt + (size_t)bh * 64 * 2048;

  unsigned short* Pw = &Plds[w][0];
  const int swz = lc & 7;
  unsigned short* pws = Pw + lc * 64 + 4 * (lr & 1);
  const int rsw = swz << 3;

  const int srow = t >> 3;                       // 0..31
  const int scol = ((t & 7) ^ (srow & 7)) << 3;  // pre-swizzled source col

#define STAGE(bufi, kb_)                                                        \
  {                                                                             \
    gload16(Kg + (size_t)((kb_) + srow) * 64 + scol,        Ks[bufi] + t * 8);  \
    gload16(Kg + (size_t)((kb_) + 32 + srow) * 64 + scol,   Ks[bufi] + 2048 + t * 8); \
    gload16(Vg + (size_t)srow * 2048 + (kb_) + scol,        Vs[bufi] + t * 8);  \
    gload16(Vg + (size_t)(32 + srow) * 2048 + (kb_) + scol, Vs[bufi] + 2048 + t * 8); \
  }

  STAGE(0, 0);
  STAGE(1, 64);
  int cur = 0;

#pragma unroll 1
  for (int kt = 0; kt < 32; ++kt) {
    // wait for OWN loads of tile kt (leave next tile's 4 in flight), then join
    if (kt < 30) { asm volatile("s_waitcnt vmcnt(4)" ::: "memory"); }
    else         { asm volatile("s_waitcnt vmcnt(0)" ::: "memory"); }
    __builtin_amdgcn_s_barrier();

    const unsigned short* KsC = Ks[cur];
    const unsigned short* VsC = Vs[cur];

    // S^T = K * Q^T : sc[c][r] = S[key = c*16 + lr*4 + r][q = q0 + lc]
    f32x4 sc[4];
    __builtin_amdgcn_s_setprio(1);
#pragma unroll
    for (int c = 0; c < 4; ++c) {
      const unsigned short* kp = KsC + (c * 16 + lc) * 64;
      bfrag k0 = *(const bfrag*)(kp + ((lr * 8) ^ rsw));
      bfrag k1 = *(const bfrag*)(kp + ((32 + lr * 8) ^ rsw));
      f32x4 z = (f32x4){0.f, 0.f, 0.f, 0.f};
      z = MFMA16(k0, aq0, z);          // swapped operands: rows = keys
      sc[c] = MFMA16(k1, aq1, z);
    }
    __builtin_amdgcn_s_setprio(0);

    // P = exp2(S) directly (no max subtraction); accumulate q-row sum
#pragma unroll
    for (int c = 0; c < 4; ++c)
#pragma unroll
      for (int r = 0; r < 4; ++r)
        sc[c][r] = __builtin_amdgcn_exp2f(sc[c][r]);
    {
      float s0 = (sc[0][0] + sc[0][1]) + (sc[0][2] + sc[0][3]);
      float s1 = (sc[1][0] + sc[1][1]) + (sc[1][2] + sc[1][3]);
      float s2 = (sc[2][0] + sc[2][1]) + (sc[2][2] + sc[2][3]);
      float s3 = (sc[3][0] + sc[3][1]) + (sc[3][2] + sc[3][3]);
      lsum += (s0 + s1) + (s2 + s3);
    }

    // P -> LDS [q][key]: lane's 4 r-values are keys c*16+lr*4..+3 of row lc.
    // 8-elem-unit XOR swizzle by (lc&7) matches the b128 read below.
#pragma unroll
    for (int c = 0; c < 4; ++c) {
      unsigned pk0, pk1;
      asm("v_cvt_pk_bf16_f32 %0, %1, %2" : "=v"(pk0) : "v"(sc[c][0]), "v"(sc[c][1]));
      asm("v_cvt_pk_bf16_f32 %0, %1, %2" : "=v"(pk1) : "v"(sc[c][2]), "v"(sc[c][3]));
      u32x2 pk; pk.x = pk0; pk.y = pk1;
      *(u32x2*)(pws + (((2 * c + (lr >> 1)) ^ swz) << 3)) = pk;
    }

    // A-frag read: P[q=lc][keys ks*32 + lr*8 .. +7]
    bfrag ap0 = *(const bfrag*)(Pw + lc * 64 + ((lr ^ swz) << 3));
    bfrag ap1 = *(const bfrag*)(Pw + lc * 64 + (((4 + lr) ^ swz) << 3));

    // O += P * V   (V^T tile: B[col=d][k=key])
    __builtin_amdgcn_s_setprio(1);
#pragma unroll
    for (int n = 0; n < 4; ++n) {
      const unsigned short* vp = VsC + (n * 16 + lc) * 64;
      bfrag bv0 = *(const bfrag*)(vp + ((lr * 8) ^ rsw));
      bfrag bv1 = *(const bfrag*)(vp + ((32 + lr * 8) ^ rsw));
      acc[n] = MFMA16(ap0, bv0, acc[n]);
      acc[n] = MFMA16(ap1, bv1, acc[n]);
    }
    __builtin_amdgcn_s_setprio(0);

    // all waves done reading buf[cur] -> safe to overwrite with tile kt+2
    __builtin_amdgcn_s_barrier();
    if (kt + 2 < 32) STAGE(cur, (kt + 2) * 64);
    cur ^= 1;
  }
#undef STAGE

  // reduce lsum over the 4 lr-lanes (each covered 16 of 64 keys per iter)
  float v = lsum;
  v += __shfl_xor(v, 16);
  v += __shfl_xor(v, 32);          // v = total row-sum for q = q0 + lc
  float inv[4];
#pragma unroll
  for (int r = 0; r < 4; ++r)
    inv[r] = 1.0f / __shfl(v, lr * 4 + r);   // fetch row-sum for q = lr*4+r

  // store O in (B,S,H,D) bf16; lane holds O[q=lr*4+r][d=n*16+lc]
  const int b = bh >> 4, h = bh & 15;
#pragma unroll
  for (int r = 0; r < 4; ++r) {
    int s = q0 + lr * 4 + r;
    size_t base = (((size_t)b * 2048 + s) * 16 + h) * 64;
#pragma unroll
    for (int n = 0; n < 4; ++n)
      O[base + n * 16 + lc] = f2bf(acc[n][r] * inv[r]);
  }
}

// ---------------------------------------------------------------------------
// K5: output projection.  out = O @ Wo^T + bo   (fp32 out, row-major 8192x1024)
// ---------------------------------------------------------------------------
__global__ __launch_bounds__(256) void gemm_out(
    const unsigned short* __restrict__ Ob, const unsigned short* __restrict__ Wo,
    const float* __restrict__ bias, float* __restrict__ out) {
  __shared__ unsigned short As[128 * 64];
  __shared__ unsigned short Bs[128 * 64];
  const int t = threadIdx.x;
  const int lane = t & 63, w = t >> 6;
  const int wr = w >> 1, wc = w & 1;
  const int lc = lane & 15, lr = lane >> 4;
  const int m0 = blockIdx.y * 128, n0 = blockIdx.x * 128;

  const int arow = t >> 3;
  const int acol = ((t & 7) << 3) ^ ((arow & 7) << 3);
  const unsigned short* gA = Ob + (size_t)(m0 + arow) * 1024 + acol;
  const unsigned short* gB = Wo + (size_t)(n0 + arow) * 1024 + acol;
  unsigned short* lA = As + t * 8;
  unsigned short* lB = Bs + t * 8;

  f32x4 acc[4][4];
#pragma unroll
  for (int m = 0; m < 4; ++m)
#pragma unroll
    for (int n = 0; n < 4; ++n) acc[m][n] = (f32x4){0.f, 0.f, 0.f, 0.f};

  const int rsw = (lc & 7) << 3;

#pragma unroll 1
  for (int kt = 0; kt < 16; ++kt) {
    __syncthreads();
#pragma unroll
    for (int c = 0; c < 4; ++c) {
      gload16(gA + (size_t)c * 32 * 1024, lA + c * 2048);
      gload16(gB + (size_t)c * 32 * 1024, lB + c * 2048);
    }
    gA += 64; gB += 64;
    __syncthreads();
#pragma unroll
    for (int ks = 0; ks < 2; ++ks) {
      bfrag af[4], bfr[4];
#pragma unroll
      for (int i = 0; i < 4; ++i)
        af[i] = *(const bfrag*)(As + (wr * 64 + i * 16 + lc) * 64 + ((ks * 32 + lr * 8) ^ rsw));
#pragma unroll
      for (int i = 0; i < 4; ++i)
        bfr[i] = *(const bfrag*)(Bs + (wc * 64 + i * 16 + lc) * 64 + ((ks * 32 + lr * 8) ^ rsw));
#pragma unroll
      for (int m = 0; m < 4; ++m)
#pragma unroll
        for (int n = 0; n < 4; ++n)
          acc[m][n] = MFMA16(af[m], bfr[n], acc[m][n]);
    }
  }
#pragma unroll
  for (int n = 0; n < 4; ++n) {
    int col = n0 + wc * 64 + n * 16 + lc;
    float bv = bias[col];
#pragma unroll
    for (int m = 0; m < 4; ++m) {
#pragma unroll
      for (int r = 0; r < 4; ++r) {
        int row = m0 + wr * 64 + m * 16 + lr * 4 + r;
        out[(size_t)row * 1024 + col] = acc[m][n][r] + bv;
      }
    }
  }
}

// ---------------------------------------------------------------------------
extern "C" void kernel_launch(void* const* d_in, const int* in_sizes, int n_in,
                              void* d_out, int out_size, void* d_ws, size_t ws_size,
                              hipStream_t stream) {
  (void)in_sizes; (void)n_in; (void)out_size; (void)ws_size;
  const float* x  = (const float*)d_in[0];
  const float* wq = (const float*)d_in[1];
  const float* bq = (const float*)d_in[2];
  const float* wk = (const float*)d_in[3];
  const float* bk = (const float*)d_in[4];
  const float* wv = (const float*)d_in[5];
  const float* bv = (const float*)d_in[6];
  const float* wo = (const float*)d_in[7];
  const float* bo = (const float*)d_in[8];
  float* out = (float*)d_out;

  char* ws = (char*)d_ws;
  unsigned short* Xb   = (unsigned short*)(ws);                       // 16 MB (reused as O)
  unsigned short* Wqb  = (unsigned short*)(ws + (16ull << 20));       // 2 MB
  unsigned short* Wkb  = (unsigned short*)(ws + (18ull << 20));
  unsigned short* Wvb  = (unsigned short*)(ws + (20ull << 20));
  unsigned short* Wob  = (unsigned short*)(ws + (22ull << 20));
  unsigned short* Qb   = (unsigned short*)(ws + (24ull << 20));       // 16 MB
  unsigned short* Kb   = (unsigned short*)(ws + (40ull << 20));       // 16 MB
  unsigned short* Vt   = (unsigned short*)(ws + (56ull << 20));       // 16 MB (B,H,D,S)
  float2* rope         = (float2*)(ws + (72ull << 20));               // 512 KB
  unsigned short* Ob   = Xb;   // Xb dead after QKV GEMM

  prep_kernel<<<dim3(1024, 6), 256, 0, stream>>>(x, wq, wk, wv, wo,
                                                 Xb, Wqb, Wkb, Wvb, Wob, rope);
  gemm_qkv<<<dim3(8, 64, 3), 256, 0, stream>>>(Xb, Wqb, Wkb, Wvb,
                                               bq, bk, bv, rope, Qb, Kb, Vt);
  attn_kernel<<<2048, 256, 0, stream>>>(Qb, Kb, Vt, Ob);
  gemm_out<<<dim3(8, 64), 256, 0, stream>>>(Ob, Wob, bo, out);
}

// Round 9
// 205.761 us; speedup vs baseline: 1.0763x; 1.0763x over previous
//
#include <hip/hip_runtime.h>

// ---------------------------------------------------------------------------
// RoPE Multihead Self-Attention  B=4 S=2048 E=1024 H=16 D=64  (bf16 internal)
// ---------------------------------------------------------------------------

typedef __attribute__((ext_vector_type(4))) float f32x4;
typedef __attribute__((ext_vector_type(8))) short bfrag;   // 8 x bf16 (4 VGPR)
typedef __attribute__((ext_vector_type(4))) short svec4;
typedef __attribute__((ext_vector_type(2))) unsigned int u32x2;

#define MFMA16(a, b, c) __builtin_amdgcn_mfma_f32_16x16x32_bf16(a, b, c, 0, 0, 0)

__device__ __forceinline__ unsigned short f2bf(float f) {
  unsigned u = __builtin_bit_cast(unsigned, f);
  u += 0x7FFFu + ((u >> 16) & 1u);            // round-to-nearest-even
  return (unsigned short)(u >> 16);
}

// async global->LDS, 16B per lane
__device__ __forceinline__ void gload16(const void* g, void* l) {
  __builtin_amdgcn_global_load_lds(
      (const __attribute__((address_space(1))) unsigned int*)g,
      (__attribute__((address_space(3))) unsigned int*)l, 16, 0, 0);
}

// ---------------------------------------------------------------------------
// K0: fp32 -> bf16 conversion of x and 4 weights + RoPE cos/sin table
// ---------------------------------------------------------------------------
__global__ __launch_bounds__(256) void prep_kernel(
    const float* __restrict__ x, const float* __restrict__ wq,
    const float* __restrict__ wk, const float* __restrict__ wv,
    const float* __restrict__ wo,
    unsigned short* __restrict__ xb, unsigned short* __restrict__ wqb,
    unsigned short* __restrict__ wkb, unsigned short* __restrict__ wvb,
    unsigned short* __restrict__ wob, float2* __restrict__ rope) {
  const int y = blockIdx.y;
  const int tid = blockIdx.x * blockDim.x + threadIdx.x;
  const int stride = gridDim.x * blockDim.x;
  if (y < 5) {
    const float* src = y == 0 ? x : y == 1 ? wq : y == 2 ? wk : y == 3 ? wv : wo;
    unsigned short* dst = y == 0 ? xb : y == 1 ? wqb : y == 2 ? wkb : y == 3 ? wvb : wob;
    const int n4 = (y == 0 ? (8192 * 1024) : (1024 * 1024)) >> 2;
    for (int i = tid; i < n4; i += stride) {
      float4 v = ((const float4*)src)[i];
      svec4 o;
      o.x = (short)f2bf(v.x); o.y = (short)f2bf(v.y);
      o.z = (short)f2bf(v.z); o.w = (short)f2bf(v.w);
      ((svec4*)dst)[i] = o;
    }
  } else {
    for (int i = tid; i < 2048 * 32; i += stride) {
      int s = i >> 5, f = i & 31;
      float invf = powf(10000.0f, -(float)f * (1.0f / 32.0f));
      float ang = (float)s * invf;
      rope[i] = make_float2(cosf(ang), sinf(ang));
    }
  }
}

// ---------------------------------------------------------------------------
// K1: QKV projection GEMM with fused RoPE (Q,K) and fused transpose (V).
// ---------------------------------------------------------------------------
__global__ __launch_bounds__(256) void gemm_qkv(
    const unsigned short* __restrict__ Xb,
    const unsigned short* __restrict__ Wq, const unsigned short* __restrict__ Wk,
    const unsigned short* __restrict__ Wv,
    const float* __restrict__ biasq, const float* __restrict__ biask,
    const float* __restrict__ biasv,
    const float2* __restrict__ rope,
    unsigned short* __restrict__ Qo, unsigned short* __restrict__ Ko,
    unsigned short* __restrict__ Vto) {
  const int z = blockIdx.z;
  __shared__ unsigned short As[128 * 64];
  __shared__ unsigned short Bs[128 * 64];
  const int t = threadIdx.x;
  const int lane = t & 63, w = t >> 6;
  const int wr = w >> 1, wc = w & 1;
  const int lc = lane & 15, lr = lane >> 4;

  int m0, n0;
  const unsigned short *Apt, *Bpt;
  if (z == 0)      { m0 = blockIdx.y * 128; n0 = blockIdx.x * 128; Apt = Xb; Bpt = Wq; }
  else if (z == 1) { m0 = blockIdx.y * 128; n0 = blockIdx.x * 128; Apt = Xb; Bpt = Wk; }
  else             { m0 = blockIdx.x * 128; n0 = blockIdx.y * 128; Apt = Wv; Bpt = Xb; }

  const int arow = t >> 3;
  const int acol = ((t & 7) << 3) ^ ((arow & 7) << 3);   // pre-swizzled source col
  const unsigned short* gA = Apt + (size_t)(m0 + arow) * 1024 + acol;
  const unsigned short* gB = Bpt + (size_t)(n0 + arow) * 1024 + acol;
  unsigned short* lA = As + t * 8;
  unsigned short* lB = Bs + t * 8;

  f32x4 acc[4][4];
#pragma unroll
  for (int m = 0; m < 4; ++m)
#pragma unroll
    for (int n = 0; n < 4; ++n) acc[m][n] = (f32x4){0.f, 0.f, 0.f, 0.f};

  const int rsw = (lc & 7) << 3;

#pragma unroll 1
  for (int kt = 0; kt < 16; ++kt) {
    __syncthreads();
#pragma unroll
    for (int c = 0; c < 4; ++c) {
      gload16(gA + (size_t)c * 32 * 1024, lA + c * 2048);
      gload16(gB + (size_t)c * 32 * 1024, lB + c * 2048);
    }
    gA += 64; gB += 64;
    __syncthreads();
#pragma unroll
    for (int ks = 0; ks < 2; ++ks) {
      bfrag af[4], bfr[4];
#pragma unroll
      for (int i = 0; i < 4; ++i)
        af[i] = *(const bfrag*)(As + (wr * 64 + i * 16 + lc) * 64 + ((ks * 32 + lr * 8) ^ rsw));
#pragma unroll
      for (int i = 0; i < 4; ++i)
        bfr[i] = *(const bfrag*)(Bs + (wc * 64 + i * 16 + lc) * 64 + ((ks * 32 + lr * 8) ^ rsw));
#pragma unroll
      for (int m = 0; m < 4; ++m)
#pragma unroll
        for (int n = 0; n < 4; ++n)
          acc[m][n] = MFMA16(af[m], bfr[n], acc[m][n]);
    }
  }

  if (z < 2) {
    // bias + RoPE + (Q only) 0.125*log2e scale; scatter to (B,H,S,D)
    const float* bias = (z == 0) ? biasq : biask;
    unsigned short* dst = (z == 0) ? Qo : Ko;
    const float qs = (z == 0) ? 0.125f * 1.44269504f : 1.0f;
    const int h = (n0 + wc * 64) >> 6;
#pragma unroll
    for (int m = 0; m < 4; ++m) {
#pragma unroll
      for (int r = 0; r < 4; ++r) {
        int row = m0 + wr * 64 + m * 16 + lr * 4 + r;   // token
        int b = row >> 11, s = row & 2047;
        const float2* trow = rope + (s << 5);
        size_t base = ((size_t)((b << 4) + h) * 2048 + s) * 64;
#pragma unroll
        for (int n = 0; n < 2; ++n) {
          int col1 = n0 + wc * 64 + n * 16 + lc;
          int d = n * 16 + lc;                           // < 32
          float a  = acc[m][n][r]     + bias[col1];
          float bb = acc[m][n + 2][r] + bias[col1 + 32];
          float2 t0 = trow[d >> 1];
          float2 t1 = trow[16 + (d >> 1)];
          dst[base + d]      = f2bf((a * t0.x - bb * t0.y) * qs);
          dst[base + d + 32] = f2bf((bb * t1.x + a * t1.y) * qs);
        }
      }
    }
  } else {
    // V: C[wcol][token] -> Vt (B,H,D,S)
#pragma unroll
    for (int m = 0; m < 4; ++m) {
#pragma unroll
      for (int r = 0; r < 4; ++r) {
        int wcol = m0 + wr * 64 + m * 16 + lr * 4 + r;
        float bv = biasv[wcol];
        int h = wcol >> 6, d = wcol & 63;
#pragma unroll
        for (int n = 0; n < 4; ++n) {
          int token = n0 + wc * 64 + n * 16 + lc;
          int b = token >> 11, s = token & 2047;
          Vto[((size_t)((b << 4) + h) * 64 + d) * 2048 + s] = f2bf(acc[m][n][r] + bv);
        }
      }
    }
  }
}

// ---------------------------------------------------------------------------
// K4: flash attention, 8-WAVE BLOCK (512 thr), 32 q-rows/wave = 256 q/block.
// Per-wave body copied from PASSING round 5 (two q-halves, DISJOINT P halves,
// V-frags shared in registers).  Loop scheme from PASSING round 8 (2-deep
// counted-vmcnt prefetch, raw s_barrier, no vmcnt(0) drain in main loop).
// Staging amortized over 512 threads: 2 gload16/thread/iter (4x less issue
// per unit work than round 8).  LDS = 16K(Ks)+16K(Vs)+32K(P) = 65536 B
// -> 2 blocks/CU; grid 512 = exactly 2x256, zero dispatch tail.
// ---------------------------------------------------------------------------
__global__ __launch_bounds__(512) void attn_kernel(
    const unsigned short* __restrict__ Q, const unsigned short* __restrict__ K,
    const unsigned short* __restrict__ Vt, unsigned short* __restrict__ O) {
  __shared__ unsigned short Ks[2][64 * 64];
  __shared__ unsigned short Vs[2][64 * 64];
  __shared__ unsigned short Plds[8][32 * 64];   // per-wave [q=32][key=64]
  const int t = threadIdx.x;
  const int lane = t & 63, w = t >> 6;          // w = 0..7
  const int lc = lane & 15, lr = lane >> 4;
  const int bid = blockIdx.x;                   // 512 = 64 bh x 8 qblocks
  const int xcd = bid & 7;
  const int jj = bid >> 3;                      // 0..63
  const int bh = xcd * 8 + (jj >> 3);           // 8 heads per XCD
  const int qb = jj & 7;
  const int q0 = qb * 256 + w * 32;

  const unsigned short* Qp = Q + ((size_t)bh * 2048 + q0 + lc) * 64 + lr * 8;
  bfrag aq00 = *(const bfrag*)Qp;               // q=q0+lc,    d=lr*8..
  bfrag aq01 = *(const bfrag*)(Qp + 32);
  bfrag aq10 = *(const bfrag*)(Qp + 16 * 64);   // q=q0+16+lc
  bfrag aq11 = *(const bfrag*)(Qp + 16 * 64 + 32);

  f32x4 acc0[4], acc1[4];
#pragma unroll
  for (int n = 0; n < 4; ++n) {
    acc0[n] = (f32x4){0.f, 0.f, 0.f, 0.f};
    acc1[n] = (f32x4){0.f, 0.f, 0.f, 0.f};
  }
  float lsum0 = 0.f, lsum1 = 0.f;

  const unsigned short* Kg = K + (size_t)bh * 2048 * 64;
  const unsigned short* Vg = Vt + (size_t)bh * 64 * 2048;

  unsigned short* Pw = &Plds[w][0];
  const int swz = lc & 7;
  unsigned short* pws0 = Pw + lc * 64 + 4 * (lr & 1);          // qh=0 rows
  unsigned short* pws1 = pws0 + 16 * 64;                       // qh=1 rows
  const int rsw = swz << 3;

  // 512-thread staging: thread t -> LDS linear slot t*16B = row t>>3, unit t&7
  const int srow = t >> 3;                       // 0..63 (full tile, one pass)
  const int scol = ((t & 7) ^ (srow & 7)) << 3;  // pre-swizzled source col

#define STAGE(bufi, kb_)                                                      \
  {                                                                           \
    gload16(Kg + (size_t)((kb_) + srow) * 64 + scol,   Ks[bufi] + t * 8);     \
    gload16(Vg + (size_t)srow * 2048 + (kb_) + scol,   Vs[bufi] + t * 8);     \
  }

  STAGE(0, 0);
  STAGE(1, 64);
  int cur = 0;

#pragma unroll 1
  for (int kt = 0; kt < 32; ++kt) {
    // wait for OWN tile's 2 loads (leave next tile's 2 in flight), then join
    if (kt < 30) { asm volatile("s_waitcnt vmcnt(2)" ::: "memory"); }
    else         { asm volatile("s_waitcnt vmcnt(0)" ::: "memory"); }
    __builtin_amdgcn_s_barrier();

    const unsigned short* KsC = Ks[cur];
    const unsigned short* VsC = Vs[cur];

    // S^T = K * Q^T for both q-halves: sc[c][r] = S[key=c*16+lr*4+r][q]
    f32x4 sc0[4], sc1[4];
    __builtin_amdgcn_s_setprio(1);
#pragma unroll
    for (int c = 0; c < 4; ++c) {
      const unsigned short* kp = KsC + (c * 16 + lc) * 64;
      bfrag k0 = *(const bfrag*)(kp + ((lr * 8) ^ rsw));
      bfrag k1 = *(const bfrag*)(kp + ((32 + lr * 8) ^ rsw));
      f32x4 z0 = (f32x4){0.f, 0.f, 0.f, 0.f};
      z0 = MFMA16(k0, aq00, z0);
      sc0[c] = MFMA16(k1, aq01, z0);
      f32x4 z1 = (f32x4){0.f, 0.f, 0.f, 0.f};
      z1 = MFMA16(k0, aq10, z1);
      sc1[c] = MFMA16(k1, aq11, z1);
    }
    __builtin_amdgcn_s_setprio(0);

    // P = exp2(S); accumulate q-row sums
#pragma unroll
    for (int c = 0; c < 4; ++c)
#pragma unroll
      for (int r = 0; r < 4; ++r) {
        sc0[c][r] = __builtin_amdgcn_exp2f(sc0[c][r]);
        sc1[c][r] = __builtin_amdgcn_exp2f(sc1[c][r]);
      }
#pragma unroll
    for (int c = 0; c < 4; ++c) {
      lsum0 += (sc0[c][0] + sc0[c][1]) + (sc0[c][2] + sc0[c][3]);
      lsum1 += (sc1[c][0] + sc1[c][1]) + (sc1[c][2] + sc1[c][3]);
    }

    // P -> LDS [q][key], 8-elem-unit XOR swizzle by (lc&7); disjoint halves
#pragma unroll
    for (int c = 0; c < 4; ++c) {
      int off = ((2 * c + (lr >> 1)) ^ swz) << 3;
      unsigned a0, a1, b0, b1;
      asm("v_cvt_pk_bf16_f32 %0, %1, %2" : "=v"(a0) : "v"(sc0[c][0]), "v"(sc0[c][1]));
      asm("v_cvt_pk_bf16_f32 %0, %1, %2" : "=v"(a1) : "v"(sc0[c][2]), "v"(sc0[c][3]));
      asm("v_cvt_pk_bf16_f32 %0, %1, %2" : "=v"(b0) : "v"(sc1[c][0]), "v"(sc1[c][1]));
      asm("v_cvt_pk_bf16_f32 %0, %1, %2" : "=v"(b1) : "v"(sc1[c][2]), "v"(sc1[c][3]));
      u32x2 p0; p0.x = a0; p0.y = a1;
      u32x2 p1; p1.x = b0; p1.y = b1;
      *(u32x2*)(pws0 + off) = p0;
      *(u32x2*)(pws1 + off) = p1;
    }

    // A-frag reads: P[q][keys ks*32 + lr*8 .. +7]
    bfrag ap00 = *(const bfrag*)(Pw + lc * 64 + ((lr ^ swz) << 3));
    bfrag ap01 = *(const bfrag*)(Pw + lc * 64 + (((4 + lr) ^ swz) << 3));
    bfrag ap10 = *(const bfrag*)(Pw + (16 + lc) * 64 + ((lr ^ swz) << 3));
    bfrag ap11 = *(const bfrag*)(Pw + (16 + lc) * 64 + (((4 + lr) ^ swz) << 3));

    // O += P * V   (V-frags loaded once, shared across both q-halves)
    __builtin_amdgcn_s_setprio(1);
#pragma unroll
    for (int n = 0; n < 4; ++n) {
      const unsigned short* vp = VsC + (n * 16 + lc) * 64;
      bfrag bv0 = *(const bfrag*)(vp + ((lr * 8) ^ rsw));
      bfrag bv1 = *(const bfrag*)(vp + ((32 + lr * 8) ^ rsw));
      acc0[n] = MFMA16(ap00, bv0, acc0[n]);
      acc0[n] = MFMA16(ap01, bv1, acc0[n]);
      acc1[n] = MFMA16(ap10, bv0, acc1[n]);
      acc1[n] = MFMA16(ap11, bv1, acc1[n]);
    }
    __builtin_amdgcn_s_setprio(0);

    // all waves done reading buf[cur] -> safe to overwrite with tile kt+2
    __builtin_amdgcn_s_barrier();
    if (kt + 2 < 32) STAGE(cur, (kt + 2) * 64);
    cur ^= 1;
  }
#undef STAGE

  // reduce lsum over the 4 lr-lanes, redistribute per output row
  float v0 = lsum0, v1 = lsum1;
  v0 += __shfl_xor(v0, 16); v0 += __shfl_xor(v0, 32);
  v1 += __shfl_xor(v1, 16); v1 += __shfl_xor(v1, 32);
  float inv0[4], inv1[4];
#pragma unroll
  for (int r = 0; r < 4; ++r) {
    inv0[r] = 1.0f / __shfl(v0, lr * 4 + r);
    inv1[r] = 1.0f / __shfl(v1, lr * 4 + r);
  }

  // store O in (B,S,H,D) bf16; lane holds O[q=qh*16+lr*4+r][d=n*16+lc]
  const int b = bh >> 4, h = bh & 15;
#pragma unroll
  for (int r = 0; r < 4; ++r) {
    int s0 = q0 + lr * 4 + r;
    size_t base0 = (((size_t)b * 2048 + s0) * 16 + h) * 64;
    size_t base1 = (((size_t)b * 2048 + s0 + 16) * 16 + h) * 64;
#pragma unroll
    for (int n = 0; n < 4; ++n) {
      O[base0 + n * 16 + lc] = f2bf(acc0[n][r] * inv0[r]);
      O[base1 + n * 16 + lc] = f2bf(acc1[n][r] * inv1[r]);
    }
  }
}

// ---------------------------------------------------------------------------
// K5: output projection.  out = O @ Wo^T + bo   (fp32 out, row-major 8192x1024)
// ---------------------------------------------------------------------------
__global__ __launch_bounds__(256) void gemm_out(
    const unsigned short* __restrict__ Ob, const unsigned short* __restrict__ Wo,
    const float* __restrict__ bias, float* __restrict__ out) {
  __shared__ unsigned short As[128 * 64];
  __shared__ unsigned short Bs[128 * 64];
  const int t = threadIdx.x;
  const int lane = t & 63, w = t >> 6;
  const int wr = w >> 1, wc = w & 1;
  const int lc = lane & 15, lr = lane >> 4;
  const int m0 = blockIdx.y * 128, n0 = blockIdx.x * 128;

  const int arow = t >> 3;
  const int acol = ((t & 7) << 3) ^ ((arow & 7) << 3);
  const unsigned short* gA = Ob + (size_t)(m0 + arow) * 1024 + acol;
  const unsigned short* gB = Wo + (size_t)(n0 + arow) * 1024 + acol;
  unsigned short* lA = As + t * 8;
  unsigned short* lB = Bs + t * 8;

  f32x4 acc[4][4];
#pragma unroll
  for (int m = 0; m < 4; ++m)
#pragma unroll
    for (int n = 0; n < 4; ++n) acc[m][n] = (f32x4){0.f, 0.f, 0.f, 0.f};

  const int rsw = (lc & 7) << 3;

#pragma unroll 1
  for (int kt = 0; kt < 16; ++kt) {
    __syncthreads();
#pragma unroll
    for (int c = 0; c < 4; ++c) {
      gload16(gA + (size_t)c * 32 * 1024, lA + c * 2048);
      gload16(gB + (size_t)c * 32 * 1024, lB + c * 2048);
    }
    gA += 64; gB += 64;
    __syncthreads();
#pragma unroll
    for (int ks = 0; ks < 2; ++ks) {
      bfrag af[4], bfr[4];
#pragma unroll
      for (int i = 0; i < 4; ++i)
        af[i] = *(const bfrag*)(As + (wr * 64 + i * 16 + lc) * 64 + ((ks * 32 + lr * 8) ^ rsw));
#pragma unroll
      for (int i = 0; i < 4; ++i)
        bfr[i] = *(const bfrag*)(Bs + (wc * 64 + i * 16 + lc) * 64 + ((ks * 32 + lr * 8) ^ rsw));
#pragma unroll
      for (int m = 0; m < 4; ++m)
#pragma unroll
        for (int n = 0; n < 4; ++n)
          acc[m][n] = MFMA16(af[m], bfr[n], acc[m][n]);
    }
  }
#pragma unroll
  for (int n = 0; n < 4; ++n) {
    int col = n0 + wc * 64 + n * 16 + lc;
    float bv = bias[col];
#pragma unroll
    for (int m = 0; m < 4; ++m) {
#pragma unroll
      for (int r = 0; r < 4; ++r) {
        int row = m0 + wr * 64 + m * 16 + lr * 4 + r;
        out[(size_t)row * 1024 + col] = acc[m][n][r] + bv;
      }
    }
  }
}

// ---------------------------------------------------------------------------
extern "C" void kernel_launch(void* const* d_in, const int* in_sizes, int n_in,
                              void* d_out, int out_size, void* d_ws, size_t ws_size,
                              hipStream_t stream) {
  (void)in_sizes; (void)n_in; (void)out_size; (void)ws_size;
  const float* x  = (const float*)d_in[0];
  const float* wq = (const float*)d_in[1];
  const float* bq = (const float*)d_in[2];
  const float* wk = (const float*)d_in[3];
  const float* bk = (const float*)d_in[4];
  const float* wv = (const float*)d_in[5];
  const float* bv = (const float*)d_in[6];
  const float* wo = (const float*)d_in[7];
  const float* bo = (const float*)d_in[8];
  float* out = (float*)d_out;

  char* ws = (char*)d_ws;
  unsigned short* Xb   = (unsigned short*)(ws);                       // 16 MB (reused as O)
  unsigned short* Wqb  = (unsigned short*)(ws + (16ull << 20));       // 2 MB
  unsigned short* Wkb  = (unsigned short*)(ws + (18ull << 20));
  unsigned short* Wvb  = (unsigned short*)(ws + (20ull << 20));
  unsigned short* Wob  = (unsigned short*)(ws + (22ull << 20));
  unsigned short* Qb   = (unsigned short*)(ws + (24ull << 20));       // 16 MB
  unsigned short* Kb   = (unsigned short*)(ws + (40ull << 20));       // 16 MB
  unsigned short* Vt   = (unsigned short*)(ws + (56ull << 20));       // 16 MB (B,H,D,S)
  float2* rope         = (float2*)(ws + (72ull << 20));               // 512 KB
  unsigned short* Ob   = Xb;   // Xb dead after QKV GEMM

  prep_kernel<<<dim3(1024, 6), 256, 0, stream>>>(x, wq, wk, wv, wo,
                                                 Xb, Wqb, Wkb, Wvb, Wob, rope);
  gemm_qkv<<<dim3(8, 64, 3), 256, 0, stream>>>(Xb, Wqb, Wkb, Wvb,
                                               bq, bk, bv, rope, Qb, Kb, Vt);
  attn_kernel<<<512, 512, 0, stream>>>(Qb, Kb, Vt, Ob);
  gemm_out<<<dim3(8, 64), 256, 0, stream>>>(Ob, Wob, bo, out);
}